// Round 14
// baseline (173.245 us; speedup 1.0000x reference)
//
#include <hip/hip_runtime.h>

#define NN   100000
#define NE   1600000
#define CIN  128
#define K2   256
#define COUT 128

typedef __attribute__((ext_vector_type(8))) short bf16x8;
typedef __attribute__((ext_vector_type(4))) float f32x4;

__device__ __forceinline__ ushort f2bf(float f) {
    union { float f; unsigned u; } v; v.f = f;
    unsigned r = (v.u + 0x7FFFu + ((v.u >> 16) & 1u)) >> 16;
    return (ushort)r;
}
__device__ __forceinline__ float bflo(unsigned p) {
    union { unsigned u; float f; } v; v.u = p << 16; return v.f;
}
__device__ __forceinline__ float bfhi(unsigned p) {
    union { unsigned u; float f; } v; v.u = p & 0xFFFF0000u; return v.f;
}

// ======================= V10: quad-split p3 gather, int4 bin =======================
// rec = src (bits 0..16) | (dst & 127) << 17 ; bin f = dst>>7 (782 bins of 128 nodes)

#define NBIN     784       // bins allocated (782 used)
#define CAP3     2304      // records per bin (mean 2041, +5.8 sigma)
#define LCAP     8         // LDS staging slots per bin (k_bin)
#define NB_BIN   1024      // bin blocks
#define SRCMASK  0x1FFFF
#define SCAP     1536      // per-half-bin src list cap

// ---- W f32 -> bf16 (blocks 0-31) + gctr zeroing (block 32) ----
__global__ __launch_bounds__(256) void k_castw(const float* __restrict__ w,
                                               ushort* __restrict__ wb,
                                               int* __restrict__ gctr) {
    int t = threadIdx.x;
    if (blockIdx.x < 32) {
        int i = blockIdx.x * 256 + t;
        float4 v = *reinterpret_cast<const float4*>(w + (size_t)i * 4);
        ushort4 r; r.x = f2bf(v.x); r.y = f2bf(v.y); r.z = f2bf(v.z); r.w = f2bf(v.w);
        *reinterpret_cast<ushort4*>(wb + (size_t)i * 4) = r;
    } else {
        for (int i = t; i < NBIN + 16; i += 256) gctr[i] = 0;
    }
}

// ---- dual GEMM, shared A: yh = x@Wh^T (bf16), out = x@Wx^T + bias (f32) ----
__global__ __launch_bounds__(256) void k_gemm2(const float* __restrict__ x,
                                               const ushort* __restrict__ wb,
                                               const float* __restrict__ bias,
                                               ushort* __restrict__ yh,
                                               float* __restrict__ out) {
    int t = threadIdx.x;
    int wid = t >> 6, lane = t & 63;
    int lr = lane & 15, lk = lane >> 4;
    int row0 = blockIdx.x * 128 + wid * 32;

    f32x4 acch[2][8], accx[2][8];
    #pragma unroll
    for (int m = 0; m < 2; ++m)
        #pragma unroll
        for (int n = 0; n < 8; ++n) { acch[m][n] = (f32x4)0.f; accx[m][n] = (f32x4)0.f; }

    #pragma unroll
    for (int kb = 0; kb < 4; ++kb) {
        int kofs = kb * 32 + lk * 8;
        bf16x8 a[2];
        #pragma unroll
        for (int m = 0; m < 2; ++m) {
            int r = row0 + m * 16 + lr; if (r >= NN) r = NN - 1;
            const float* xp = x + (size_t)r * CIN + kofs;
            float4 u0 = *reinterpret_cast<const float4*>(xp);
            float4 u1 = *reinterpret_cast<const float4*>(xp + 4);
            bf16x8 aa;
            aa[0] = (short)f2bf(u0.x); aa[1] = (short)f2bf(u0.y);
            aa[2] = (short)f2bf(u0.z); aa[3] = (short)f2bf(u0.w);
            aa[4] = (short)f2bf(u1.x); aa[5] = (short)f2bf(u1.y);
            aa[6] = (short)f2bf(u1.z); aa[7] = (short)f2bf(u1.w);
            a[m] = aa;
        }
        #pragma unroll
        for (int n = 0; n < 8; ++n) {
            const ushort* wrow = wb + (size_t)(n * 16 + lr) * K2 + kofs;
            bf16x8 bh = *reinterpret_cast<const bf16x8*>(wrow);         // Wh: k in [0,128)
            bf16x8 bx = *reinterpret_cast<const bf16x8*>(wrow + CIN);   // Wx: k in [128,256)
            acch[0][n] = __builtin_amdgcn_mfma_f32_16x16x32_bf16(a[0], bh, acch[0][n], 0, 0, 0);
            acch[1][n] = __builtin_amdgcn_mfma_f32_16x16x32_bf16(a[1], bh, acch[1][n], 0, 0, 0);
            accx[0][n] = __builtin_amdgcn_mfma_f32_16x16x32_bf16(a[0], bx, accx[0][n], 0, 0, 0);
            accx[1][n] = __builtin_amdgcn_mfma_f32_16x16x32_bf16(a[1], bx, accx[1][n], 0, 0, 0);
        }
    }

    float bv[8];
    #pragma unroll
    for (int n = 0; n < 8; ++n) bv[n] = bias[n * 16 + lr];

    #pragma unroll
    for (int m = 0; m < 2; ++m)
        #pragma unroll
        for (int j = 0; j < 4; ++j) {
            int r = row0 + m * 16 + lk * 4 + j;
            if (r < NN) {
                #pragma unroll
                for (int n = 0; n < 8; ++n) {
                    yh[(size_t)r * CIN + n * 16 + lr]   = f2bf(acch[m][n][j]);
                    out[(size_t)r * COUT + n * 16 + lr] = accx[m][n][j] + bv[n];
                }
            }
        }
}

// ---- single-level binning: int4 edge reads, 1024 blocks, LDS staged ----
__global__ __launch_bounds__(256) void k_bin(const int* __restrict__ esrc,
                                             const int* __restrict__ edst,
                                             int* __restrict__ gctr,
                                             unsigned* __restrict__ gbin) {
    __shared__ unsigned lbuf[NBIN * LCAP];    // 25 KB
    __shared__ int      lcnt[NBIN];
    __shared__ int      lbase[NBIN];
    int t = threadIdx.x;
    for (int i = t; i < NBIN; i += 256) lcnt[i] = 0;
    __syncthreads();

    const int NCH = NE / 4;                   // 400000 int4 chunks
    for (int c = blockIdx.x * 256 + t; c < NCH; c += NB_BIN * 256) {
        int4 d = *reinterpret_cast<const int4*>(edst + (size_t)c * 4);
        int4 s = *reinterpret_cast<const int4*>(esrc + (size_t)c * 4);
        int dd[4] = {d.x, d.y, d.z, d.w};
        int ss[4] = {s.x, s.y, s.z, s.w};
        #pragma unroll
        for (int k = 0; k < 4; ++k) {
            int f = dd[k] >> 7;
            unsigned rec = (unsigned)ss[k] | ((unsigned)(dd[k] & 127) << 17);
            int p = atomicAdd(&lcnt[f], 1);
            if (p < LCAP) lbuf[(f << 3) + p] = rec;
            else {
                int gp = atomicAdd(&gctr[f], 1);
                if (gp < CAP3) gbin[(size_t)f * CAP3 + gp] = rec;
            }
        }
    }
    __syncthreads();

    for (int f = t; f < NBIN; f += 256) {
        int n = lcnt[f]; if (n > LCAP) n = LCAP;
        lcnt[f] = n;
        lbase[f] = (n > 0) ? atomicAdd(&gctr[f], n) : 0;
    }
    __syncthreads();

    for (int s = t; s < NBIN * LCAP; s += 256) {
        int f = s >> 3, k = s & 7;
        if (k < lcnt[f]) {
            int g0 = lbase[f] + k;
            if (g0 < CAP3) gbin[(size_t)f * CAP3 + g0] = lbuf[s];
        }
    }
}

// ---- p3: half-bin blocks (64 nodes), 2-pass sort, QUAD-split uint4 gather ----
__global__ __launch_bounds__(256) void k_p3(const int* __restrict__ gctr,
                                            const unsigned* __restrict__ gbin,
                                            const ushort* __restrict__ yh,
                                            float* __restrict__ out) {
    __shared__ int ssrc[SCAP];                // 6 KB
    __shared__ int hcnt[64];
    __shared__ int hbase[64];
    __shared__ int hcur[64];
    int f   = blockIdx.x >> 1;                // bin
    int sub = blockIdx.x & 1;                 // node half
    int t = threadIdx.x;
    int wid = t >> 6, lane = t & 63;

    if (t < 64) hcnt[t] = 0;
    __syncthreads();

    int m = gctr[f]; if (m > CAP3) m = CAP3;
    const unsigned* recs = gbin + (size_t)f * CAP3;

    // A: histogram my half's nodes (read 1)
    for (int i = t; i < m; i += 256) {
        unsigned r = recs[i];
        int node = (r >> 17) & 127;
        if ((node >> 6) == sub) atomicAdd(&hcnt[node & 63], 1);
    }
    __syncthreads();

    // B: exclusive prefix over 64 counters (wave 0)
    if (t < 64) {
        int v = hcnt[t];
        int s = v;
        #pragma unroll
        for (int d = 1; d < 64; d <<= 1) {
            int u = __shfl_up(s, d);
            if (lane >= d) s += u;
        }
        hbase[t] = s - v;
        hcur[t]  = s - v;
    }
    __syncthreads();

    // C: scatter srcs into per-node contiguous lists (read 2, L2-hot)
    for (int i = t; i < m; i += 256) {
        unsigned r = recs[i];
        int node = (r >> 17) & 127;
        if ((node >> 6) == sub) {
            int p = atomicAdd(&hcur[node & 63], 1);
            if (p < SCAP) ssrc[p] = (int)(r & SRCMASK);
        }
    }
    __syncthreads();

    // D: 16 nodes per wave; quad-split — 16 lanes/edge, uint4 loads, 4 edges/instr
    int node0 = (f << 7) + (sub << 6);
    int quad = lane >> 4;                     // 0..3
    int chof = (lane & 15) * 8;               // ushort offset: 8 channels per lane
    for (int i = wid * 16; i < wid * 16 + 16; ++i) {
        int n = node0 + i;
        if (n >= NN) break;
        int d0 = hbase[i], dg = hcnt[i];
        float a0 = 0.f, a1 = 0.f, a2 = 0.f, a3 = 0.f;
        float a4 = 0.f, a5 = 0.f, a6 = 0.f, a7 = 0.f;
        for (int e = 0; e < dg; e += 16) {
            #pragma unroll
            for (int q = 0; q < 4; ++q) {
                int idx = e + q * 4 + quad;
                uint4 v = make_uint4(0u, 0u, 0u, 0u);
                if (idx < dg) {
                    int s = ssrc[d0 + idx];
                    v = *reinterpret_cast<const uint4*>(yh + ((size_t)s << 7) + chof);
                }
                a0 += bflo(v.x); a1 += bfhi(v.x);
                a2 += bflo(v.y); a3 += bfhi(v.y);
                a4 += bflo(v.z); a5 += bfhi(v.z);
                a6 += bflo(v.w); a7 += bfhi(v.w);
            }
        }
        // reduce across the 4 quads (lane^16 then lane^32)
        a0 += __shfl(a0, lane ^ 16); a0 += __shfl(a0, lane ^ 32);
        a1 += __shfl(a1, lane ^ 16); a1 += __shfl(a1, lane ^ 32);
        a2 += __shfl(a2, lane ^ 16); a2 += __shfl(a2, lane ^ 32);
        a3 += __shfl(a3, lane ^ 16); a3 += __shfl(a3, lane ^ 32);
        a4 += __shfl(a4, lane ^ 16); a4 += __shfl(a4, lane ^ 32);
        a5 += __shfl(a5, lane ^ 16); a5 += __shfl(a5, lane ^ 32);
        a6 += __shfl(a6, lane ^ 16); a6 += __shfl(a6, lane ^ 32);
        a7 += __shfl(a7, lane ^ 16); a7 += __shfl(a7, lane ^ 32);
        float inv = (dg > 0) ? 1.0f / (float)dg : 0.0f;
        if (lane < 16) {
            float* po = out + ((size_t)n << 7) + (size_t)(lane & 15) * 8;
            f32x4* p0 = reinterpret_cast<f32x4*>(po);
            f32x4* p1 = reinterpret_cast<f32x4*>(po + 4);
            f32x4 o0 = __builtin_nontemporal_load(p0);
            f32x4 o1 = __builtin_nontemporal_load(p1);
            o0[0] += a0 * inv; o0[1] += a1 * inv; o0[2] += a2 * inv; o0[3] += a3 * inv;
            o1[0] += a4 * inv; o1[1] += a5 * inv; o1[2] += a6 * inv; o1[3] += a7 * inv;
            __builtin_nontemporal_store(o0, p0);
            __builtin_nontemporal_store(o1, p1);
        }
    }
}

// ======================= V2 fallback (round-5, validated) =======================

#define NXCD  8
#define PART  ((NN + NXCD - 1) / NXCD)
#define NB_SCAT  2048
#define NB_CAST  12500
#define NB_CASTW 32
#define CAP  64

__global__ __launch_bounds__(256) void k_fuse2(const float* __restrict__ x,
                                               const float* __restrict__ w,
                                               const int* __restrict__ src,
                                               const int* __restrict__ dst,
                                               int* __restrict__ cnt,
                                               int* __restrict__ csrF,
                                               ushort* hcat,
                                               ushort* __restrict__ wb) {
    int b = blockIdx.x, t = threadIdx.x;
    if (b < NB_SCAT) {
        int part = b & (NXCD - 1);
        int slot = b >> 3;
        int lo = part * PART;
        int hi = lo + PART; if (hi > NN) hi = NN;
        const int NCH = NE / 4;
        for (int c = slot * 256 + t; c < NCH; c += 256 * 256) {
            int4 d = *reinterpret_cast<const int4*>(dst + (size_t)c * 4);
            int4 s = *reinterpret_cast<const int4*>(src + (size_t)c * 4);
            if (d.x >= lo && d.x < hi) { int p = atomicAdd(&cnt[d.x], 1); csrF[(d.x << 6) + p] = s.x; }
            if (d.y >= lo && d.y < hi) { int p = atomicAdd(&cnt[d.y], 1); csrF[(d.y << 6) + p] = s.y; }
            if (d.z >= lo && d.z < hi) { int p = atomicAdd(&cnt[d.z], 1); csrF[(d.z << 6) + p] = s.z; }
            if (d.w >= lo && d.w < hi) { int p = atomicAdd(&cnt[d.w], 1); csrF[(d.w << 6) + p] = s.w; }
        }
    } else if (b < NB_SCAT + NB_CAST) {
        int i = (b - NB_SCAT) * 256 + t;
        int node = i >> 5, c4 = (i & 31) * 4;
        float4 v = *reinterpret_cast<const float4*>(x + (size_t)node * CIN + c4);
        ushort4 r; r.x = f2bf(v.x); r.y = f2bf(v.y); r.z = f2bf(v.z); r.w = f2bf(v.w);
        *reinterpret_cast<ushort4*>(hcat + (size_t)node * K2 + CIN + c4) = r;
    } else {
        int i = (b - NB_SCAT - NB_CAST) * 256 + t;
        float4 v = *reinterpret_cast<const float4*>(w + (size_t)i * 4);
        ushort4 r; r.x = f2bf(v.x); r.y = f2bf(v.y); r.z = f2bf(v.z); r.w = f2bf(v.w);
        *reinterpret_cast<ushort4*>(wb + (size_t)i * 4) = r;
    }
}

__global__ __launch_bounds__(256) void k_aggB(const int* __restrict__ cnt,
                                              const int* __restrict__ csrF,
                                              ushort* hcat) {
    int gw   = (blockIdx.x * 256 + threadIdx.x) >> 6;
    int lane = threadIdx.x & 63;
    if (gw >= NN) return;
    int gws = __builtin_amdgcn_readfirstlane(gw);
    int deg = cnt[gws];
    const int4* b4 = reinterpret_cast<const int4*>(csrF + ((size_t)gws << 6));
    int boff = CIN + lane * 2;
    float ax = 0.f, ay = 0.f;
    for (int e = 0; e < deg; e += 8) {
        int4 c0 = b4[(e >> 2)];
        int4 c1 = b4[(e >> 2) + 1];
        int ss[8] = {c0.x, c0.y, c0.z, c0.w, c1.x, c1.y, c1.z, c1.w};
        #pragma unroll
        for (int k = 0; k < 8; ++k) {
            bool ok = (e + k) < deg;
            int s = ok ? ss[k] : 0;
            unsigned v = *reinterpret_cast<const unsigned*>(hcat + ((size_t)s << 8) + boff);
            float mq = ok ? 1.f : 0.f;
            ax += mq * bflo(v); ay += mq * bfhi(v);
        }
    }
    float inv = (deg > 0) ? 1.0f / (float)deg : 0.0f;
    unsigned packed = (unsigned)f2bf(ax * inv) | ((unsigned)f2bf(ay * inv) << 16);
    *reinterpret_cast<unsigned*>(hcat + ((size_t)gw << 8) + lane * 2) = packed;
}

__global__ __launch_bounds__(256) void k_gemm(const ushort* hcat,
                                              const ushort* __restrict__ wb,
                                              const float* __restrict__ bias,
                                              float* out) {
    int t = threadIdx.x;
    int wid = t >> 6, lane = t & 63;
    int lr = lane & 15, lk = lane >> 4;
    int row0 = blockIdx.x * 128 + wid * 32;

    f32x4 acc[2][8];
    #pragma unroll
    for (int m = 0; m < 2; ++m)
        #pragma unroll
        for (int n = 0; n < 8; ++n) acc[m][n] = (f32x4)0.f;

    #pragma unroll
    for (int kb = 0; kb < 8; ++kb) {
        int kofs = kb * 32 + lk * 8;
        bf16x8 a[2];
        #pragma unroll
        for (int m = 0; m < 2; ++m) {
            int r = row0 + m * 16 + lr; if (r >= NN) r = NN - 1;
            a[m] = *reinterpret_cast<const bf16x8*>(hcat + ((size_t)r << 8) + kofs);
        }
        #pragma unroll
        for (int n = 0; n < 8; ++n) {
            bf16x8 bfr = *reinterpret_cast<const bf16x8*>(wb + (size_t)(n * 16 + lr) * K2 + kofs);
            acc[0][n] = __builtin_amdgcn_mfma_f32_16x16x32_bf16(a[0], bfr, acc[0][n], 0, 0, 0);
            acc[1][n] = __builtin_amdgcn_mfma_f32_16x16x32_bf16(a[1], bfr, acc[1][n], 0, 0, 0);
        }
    }

    float bv[8];
    #pragma unroll
    for (int n = 0; n < 8; ++n) bv[n] = bias[n * 16 + lr];

    #pragma unroll
    for (int m = 0; m < 2; ++m)
        #pragma unroll
        for (int j = 0; j < 4; ++j) {
            int r = row0 + m * 16 + lk * 4 + j;
            if (r < NN) {
                #pragma unroll
                for (int n = 0; n < 8; ++n)
                    out[(size_t)r * COUT + n * 16 + lr] = acc[m][n][j] + bv[n];
            }
        }
}

// ---------------- host ----------------

extern "C" void kernel_launch(void* const* d_in, const int* in_sizes, int n_in,
                              void* d_out, int out_size, void* d_ws, size_t ws_size,
                              hipStream_t stream) {
    (void)in_sizes; (void)n_in; (void)out_size;
    const float* x    = (const float*)d_in[0];
    const int*   esrc = (const int*)  d_in[1];
    const int*   edst = (const int*)  d_in[2];
    const float* wgt  = (const float*)d_in[3];
    const float* bias = (const float*)d_in[4];

    size_t ctr_ints  = 800;                              // NBIN rounded up
    size_t bin_recs  = (size_t)NBIN * CAP3;              // 1,806,336 u32
    size_t yh_elems  = (size_t)NN * CIN;                 // 12.8M ushort
    size_t need_v10 = ctr_ints * 4 + bin_recs * 4
                    + yh_elems * 2 + (size_t)K2 * COUT * 2 + 256;

    if (ws_size >= need_v10) {
        int*      wsi  = (int*)d_ws;
        int*      gctr = wsi;                            // [NBIN]
        unsigned* gbin = (unsigned*)(wsi + ctr_ints);
        ushort*   yh   = (ushort*)(gbin + bin_recs);
        ushort*   wb   = yh + yh_elems;
        float*    out  = (float*)d_out;

        k_castw<<<33, 256, 0, stream>>>(wgt, wb, gctr);  // cast + gctr zero
        k_bin  <<<NB_BIN, 256, 0, stream>>>(esrc, edst, gctr, gbin);
        k_gemm2<<<784, 256, 0, stream>>>(x, wb, bias, yh, out);
        k_p3   <<<NBIN * 2, 256, 0, stream>>>(gctr, gbin, yh, out);
    } else {
        int* wsi  = (int*)d_ws;
        int* cnt  = wsi;
        int* csrF = wsi + NN;
        ushort* wb = (ushort*)(wsi + NN + (size_t)NN * CAP);
        ushort* hcat = (ushort*)d_out;

        hipMemsetAsync(cnt, 0, (size_t)NN * sizeof(int), stream);
        k_fuse2<<<NB_SCAT + NB_CAST + NB_CASTW, 256, 0, stream>>>(
            x, wgt, esrc, edst, cnt, csrF, hcat, wb);
        k_aggB <<<NN / 4, 256, 0, stream>>>(cnt, csrF, hcat);
        k_gemm <<<(NN + 127) / 128, 256, 0, stream>>>(hcat, wb, bias, (float*)d_out);
    }
}

// Round 15
// 160.718 us; speedup vs baseline: 1.0779x; 1.0779x over previous
//
#include <hip/hip_runtime.h>

#define NN   100000
#define NE   1600000
#define CIN  128
#define K2   256
#define COUT 128

typedef __attribute__((ext_vector_type(8))) short bf16x8;
typedef __attribute__((ext_vector_type(4))) float f32x4;

__device__ __forceinline__ ushort f2bf(float f) {
    union { float f; unsigned u; } v; v.f = f;
    unsigned r = (v.u + 0x7FFFu + ((v.u >> 16) & 1u)) >> 16;
    return (ushort)r;
}
__device__ __forceinline__ float bflo(unsigned p) {
    union { unsigned u; float f; } v; v.u = p << 16; return v.f;
}
__device__ __forceinline__ float bfhi(unsigned p) {
    union { unsigned u; float f; } v; v.u = p & 0xFFFF0000u; return v.f;
}

// ======================= V11: quarter-bin p3 (occupancy probe) =======================
// rec = src (bits 0..16) | (dst & 127) << 17 ; bin f = dst>>7 (782 bins of 128 nodes)

#define NBIN     784       // bins allocated (782 used)
#define CAP3     2304      // records per bin (mean 2041, +5.8 sigma)
#define LCAP     8         // LDS staging slots per bin (k_bin)
#define NB_BIN   512       // bin blocks
#define E_BIN    3125      // edges per bin block
#define SRCMASK  0x1FFFF
#define SCAP     1024      // per-quarter-bin src list cap (mean 512, +22 sigma)

// ---- W f32 -> bf16 (blocks 0-31) + gctr zeroing (block 32) ----
__global__ __launch_bounds__(256) void k_castw(const float* __restrict__ w,
                                               ushort* __restrict__ wb,
                                               int* __restrict__ gctr) {
    int t = threadIdx.x;
    if (blockIdx.x < 32) {
        int i = blockIdx.x * 256 + t;
        float4 v = *reinterpret_cast<const float4*>(w + (size_t)i * 4);
        ushort4 r; r.x = f2bf(v.x); r.y = f2bf(v.y); r.z = f2bf(v.z); r.w = f2bf(v.w);
        *reinterpret_cast<ushort4*>(wb + (size_t)i * 4) = r;
    } else {
        for (int i = t; i < NBIN + 16; i += 256) gctr[i] = 0;
    }
}

// ---- dual GEMM, shared A: yh = x@Wh^T (bf16), out = x@Wx^T + bias (f32) ----
__global__ __launch_bounds__(256) void k_gemm2(const float* __restrict__ x,
                                               const ushort* __restrict__ wb,
                                               const float* __restrict__ bias,
                                               ushort* __restrict__ yh,
                                               float* __restrict__ out) {
    int t = threadIdx.x;
    int wid = t >> 6, lane = t & 63;
    int lr = lane & 15, lk = lane >> 4;
    int row0 = blockIdx.x * 128 + wid * 32;

    f32x4 acch[2][8], accx[2][8];
    #pragma unroll
    for (int m = 0; m < 2; ++m)
        #pragma unroll
        for (int n = 0; n < 8; ++n) { acch[m][n] = (f32x4)0.f; accx[m][n] = (f32x4)0.f; }

    #pragma unroll
    for (int kb = 0; kb < 4; ++kb) {
        int kofs = kb * 32 + lk * 8;
        bf16x8 a[2];
        #pragma unroll
        for (int m = 0; m < 2; ++m) {
            int r = row0 + m * 16 + lr; if (r >= NN) r = NN - 1;
            const float* xp = x + (size_t)r * CIN + kofs;
            float4 u0 = *reinterpret_cast<const float4*>(xp);
            float4 u1 = *reinterpret_cast<const float4*>(xp + 4);
            bf16x8 aa;
            aa[0] = (short)f2bf(u0.x); aa[1] = (short)f2bf(u0.y);
            aa[2] = (short)f2bf(u0.z); aa[3] = (short)f2bf(u0.w);
            aa[4] = (short)f2bf(u1.x); aa[5] = (short)f2bf(u1.y);
            aa[6] = (short)f2bf(u1.z); aa[7] = (short)f2bf(u1.w);
            a[m] = aa;
        }
        #pragma unroll
        for (int n = 0; n < 8; ++n) {
            const ushort* wrow = wb + (size_t)(n * 16 + lr) * K2 + kofs;
            bf16x8 bh = *reinterpret_cast<const bf16x8*>(wrow);         // Wh: k in [0,128)
            bf16x8 bx = *reinterpret_cast<const bf16x8*>(wrow + CIN);   // Wx: k in [128,256)
            acch[0][n] = __builtin_amdgcn_mfma_f32_16x16x32_bf16(a[0], bh, acch[0][n], 0, 0, 0);
            acch[1][n] = __builtin_amdgcn_mfma_f32_16x16x32_bf16(a[1], bh, acch[1][n], 0, 0, 0);
            accx[0][n] = __builtin_amdgcn_mfma_f32_16x16x32_bf16(a[0], bx, accx[0][n], 0, 0, 0);
            accx[1][n] = __builtin_amdgcn_mfma_f32_16x16x32_bf16(a[1], bx, accx[1][n], 0, 0, 0);
        }
    }

    float bv[8];
    #pragma unroll
    for (int n = 0; n < 8; ++n) bv[n] = bias[n * 16 + lr];

    #pragma unroll
    for (int m = 0; m < 2; ++m)
        #pragma unroll
        for (int j = 0; j < 4; ++j) {
            int r = row0 + m * 16 + lk * 4 + j;
            if (r < NN) {
                #pragma unroll
                for (int n = 0; n < 8; ++n) {
                    yh[(size_t)r * CIN + n * 16 + lr]   = f2bf(acch[m][n][j]);
                    out[(size_t)r * COUT + n * 16 + lr] = accx[m][n][j] + bv[n];
                }
            }
        }
}

// ---- single-level binning: edges -> 782 fine bins, LDS staged (r11-validated) ----
__global__ __launch_bounds__(256) void k_bin(const int* __restrict__ esrc,
                                             const int* __restrict__ edst,
                                             int* __restrict__ gctr,
                                             unsigned* __restrict__ gbin) {
    __shared__ unsigned lbuf[NBIN * LCAP];    // 25 KB
    __shared__ int      lcnt[NBIN];
    __shared__ int      lbase[NBIN];
    int b = blockIdx.x, t = threadIdx.x;
    for (int i = t; i < NBIN; i += 256) lcnt[i] = 0;
    __syncthreads();

    int base = b * E_BIN;
    for (int e = t; e < E_BIN; e += 256) {
        int d = edst[base + e], s = esrc[base + e];
        int f = d >> 7;
        unsigned rec = (unsigned)s | ((unsigned)(d & 127) << 17);
        int p = atomicAdd(&lcnt[f], 1);
        if (p < LCAP) lbuf[(f << 3) + p] = rec;
        else {
            int gp = atomicAdd(&gctr[f], 1);
            if (gp < CAP3) gbin[(size_t)f * CAP3 + gp] = rec;
        }
    }
    __syncthreads();

    for (int f = t; f < NBIN; f += 256) {
        int n = lcnt[f]; if (n > LCAP) n = LCAP;
        lcnt[f] = n;
        lbase[f] = (n > 0) ? atomicAdd(&gctr[f], n) : 0;
    }
    __syncthreads();

    for (int s = t; s < NBIN * LCAP; s += 256) {
        int f = s >> 3, k = s & 7;
        if (k < lcnt[f]) {
            int g0 = lbase[f] + k;
            if (g0 < CAP3) gbin[(size_t)f * CAP3 + g0] = lbuf[s];
        }
    }
}

// ---- p3: QUARTER-bin blocks (32 nodes), 2-pass global sort, r11 gather ----
__global__ __launch_bounds__(256) void k_p3(const int* __restrict__ gctr,
                                            const unsigned* __restrict__ gbin,
                                            const ushort* __restrict__ yh,
                                            float* __restrict__ out) {
    __shared__ int ssrc[SCAP];                // 4 KB
    __shared__ int hcnt[32];
    __shared__ int hbase[32];
    __shared__ int hcur[32];
    int f   = blockIdx.x >> 2;                // bin
    int sub = blockIdx.x & 3;                 // node quarter
    int t = threadIdx.x;
    int wid = t >> 6, lane = t & 63;

    if (t < 32) hcnt[t] = 0;
    __syncthreads();

    int m = gctr[f]; if (m > CAP3) m = CAP3;
    const unsigned* recs = gbin + (size_t)f * CAP3;

    // A: histogram my quarter's nodes (read 1)
    for (int i = t; i < m; i += 256) {
        unsigned r = recs[i];
        int node = (r >> 17) & 127;
        if ((node >> 5) == sub) atomicAdd(&hcnt[node & 31], 1);
    }
    __syncthreads();

    // B: exclusive prefix over 32 counters (wave 0)
    if (t < 32) {
        int v = hcnt[t];
        int s = v;
        #pragma unroll
        for (int d = 1; d < 32; d <<= 1) {
            int u = __shfl_up(s, d);
            if (lane >= d) s += u;
        }
        hbase[t] = s - v;
        hcur[t]  = s - v;
    }
    __syncthreads();

    // C: scatter srcs into per-node contiguous lists (read 2, L2-hot)
    for (int i = t; i < m; i += 256) {
        unsigned r = recs[i];
        int node = (r >> 17) & 127;
        if ((node >> 5) == sub) {
            int p = atomicAdd(&hcur[node & 31], 1);
            if (p < SCAP) ssrc[p] = (int)(r & SRCMASK);
        }
    }
    __syncthreads();

    // D: 8 nodes per wave; wave halves process 2 edges at once (r11-validated)
    int node0 = (f << 7) + (sub << 5);
    int half = lane >> 5;
    int chof = (lane & 31) * 4;               // 4 channels per lane
    for (int i = wid * 8; i < wid * 8 + 8; ++i) {
        int n = node0 + i;
        if (n >= NN) break;
        int d0 = hbase[i], dg = hcnt[i];
        float a0 = 0.f, a1 = 0.f, a2 = 0.f, a3 = 0.f;
        for (int e = 0; e < dg; e += 8) {
            #pragma unroll
            for (int q = 0; q < 4; ++q) {
                int idx = e + q * 2 + half;
                uint2 v = make_uint2(0u, 0u);
                if (idx < dg) {
                    int s = ssrc[d0 + idx];
                    v = *reinterpret_cast<const uint2*>(yh + ((size_t)s << 7) + chof);
                }
                a0 += bflo(v.x); a1 += bfhi(v.x);
                a2 += bflo(v.y); a3 += bfhi(v.y);
            }
        }
        a0 += __shfl(a0, lane ^ 32);
        a1 += __shfl(a1, lane ^ 32);
        a2 += __shfl(a2, lane ^ 32);
        a3 += __shfl(a3, lane ^ 32);
        float inv = (dg > 0) ? 1.0f / (float)dg : 0.0f;
        if (lane < 32) {
            f32x4* po = reinterpret_cast<f32x4*>(out + ((size_t)n << 7) + chof);
            f32x4 o = __builtin_nontemporal_load(po);
            o[0] += a0 * inv; o[1] += a1 * inv;
            o[2] += a2 * inv; o[3] += a3 * inv;
            __builtin_nontemporal_store(o, po);
        }
    }
}

// ======================= V2 fallback (round-5, validated) =======================

#define NXCD  8
#define PART  ((NN + NXCD - 1) / NXCD)
#define NB_SCAT  2048
#define NB_CAST  12500
#define NB_CASTW 32
#define CAP  64

__global__ __launch_bounds__(256) void k_fuse2(const float* __restrict__ x,
                                               const float* __restrict__ w,
                                               const int* __restrict__ src,
                                               const int* __restrict__ dst,
                                               int* __restrict__ cnt,
                                               int* __restrict__ csrF,
                                               ushort* hcat,
                                               ushort* __restrict__ wb) {
    int b = blockIdx.x, t = threadIdx.x;
    if (b < NB_SCAT) {
        int part = b & (NXCD - 1);
        int slot = b >> 3;
        int lo = part * PART;
        int hi = lo + PART; if (hi > NN) hi = NN;
        const int NCH = NE / 4;
        for (int c = slot * 256 + t; c < NCH; c += 256 * 256) {
            int4 d = *reinterpret_cast<const int4*>(dst + (size_t)c * 4);
            int4 s = *reinterpret_cast<const int4*>(src + (size_t)c * 4);
            if (d.x >= lo && d.x < hi) { int p = atomicAdd(&cnt[d.x], 1); csrF[(d.x << 6) + p] = s.x; }
            if (d.y >= lo && d.y < hi) { int p = atomicAdd(&cnt[d.y], 1); csrF[(d.y << 6) + p] = s.y; }
            if (d.z >= lo && d.z < hi) { int p = atomicAdd(&cnt[d.z], 1); csrF[(d.z << 6) + p] = s.z; }
            if (d.w >= lo && d.w < hi) { int p = atomicAdd(&cnt[d.w], 1); csrF[(d.w << 6) + p] = s.w; }
        }
    } else if (b < NB_SCAT + NB_CAST) {
        int i = (b - NB_SCAT) * 256 + t;
        int node = i >> 5, c4 = (i & 31) * 4;
        float4 v = *reinterpret_cast<const float4*>(x + (size_t)node * CIN + c4);
        ushort4 r; r.x = f2bf(v.x); r.y = f2bf(v.y); r.z = f2bf(v.z); r.w = f2bf(v.w);
        *reinterpret_cast<ushort4*>(hcat + (size_t)node * K2 + CIN + c4) = r;
    } else {
        int i = (b - NB_SCAT - NB_CAST) * 256 + t;
        float4 v = *reinterpret_cast<const float4*>(w + (size_t)i * 4);
        ushort4 r; r.x = f2bf(v.x); r.y = f2bf(v.y); r.z = f2bf(v.z); r.w = f2bf(v.w);
        *reinterpret_cast<ushort4*>(wb + (size_t)i * 4) = r;
    }
}

__global__ __launch_bounds__(256) void k_aggB(const int* __restrict__ cnt,
                                              const int* __restrict__ csrF,
                                              ushort* hcat) {
    int gw   = (blockIdx.x * 256 + threadIdx.x) >> 6;
    int lane = threadIdx.x & 63;
    if (gw >= NN) return;
    int gws = __builtin_amdgcn_readfirstlane(gw);
    int deg = cnt[gws];
    const int4* b4 = reinterpret_cast<const int4*>(csrF + ((size_t)gws << 6));
    int boff = CIN + lane * 2;
    float ax = 0.f, ay = 0.f;
    for (int e = 0; e < deg; e += 8) {
        int4 c0 = b4[(e >> 2)];
        int4 c1 = b4[(e >> 2) + 1];
        int ss[8] = {c0.x, c0.y, c0.z, c0.w, c1.x, c1.y, c1.z, c1.w};
        #pragma unroll
        for (int k = 0; k < 8; ++k) {
            bool ok = (e + k) < deg;
            int s = ok ? ss[k] : 0;
            unsigned v = *reinterpret_cast<const unsigned*>(hcat + ((size_t)s << 8) + boff);
            float mq = ok ? 1.f : 0.f;
            ax += mq * bflo(v); ay += mq * bfhi(v);
        }
    }
    float inv = (deg > 0) ? 1.0f / (float)deg : 0.0f;
    unsigned packed = (unsigned)f2bf(ax * inv) | ((unsigned)f2bf(ay * inv) << 16);
    *reinterpret_cast<unsigned*>(hcat + ((size_t)gw << 8) + lane * 2) = packed;
}

__global__ __launch_bounds__(256) void k_gemm(const ushort* hcat,
                                              const ushort* __restrict__ wb,
                                              const float* __restrict__ bias,
                                              float* out) {
    int t = threadIdx.x;
    int wid = t >> 6, lane = t & 63;
    int lr = lane & 15, lk = lane >> 4;
    int row0 = blockIdx.x * 128 + wid * 32;

    f32x4 acc[2][8];
    #pragma unroll
    for (int m = 0; m < 2; ++m)
        #pragma unroll
        for (int n = 0; n < 8; ++n) acc[m][n] = (f32x4)0.f;

    #pragma unroll
    for (int kb = 0; kb < 8; ++kb) {
        int kofs = kb * 32 + lk * 8;
        bf16x8 a[2];
        #pragma unroll
        for (int m = 0; m < 2; ++m) {
            int r = row0 + m * 16 + lr; if (r >= NN) r = NN - 1;
            a[m] = *reinterpret_cast<const bf16x8*>(hcat + ((size_t)r << 8) + kofs);
        }
        #pragma unroll
        for (int n = 0; n < 8; ++n) {
            bf16x8 bfr = *reinterpret_cast<const bf16x8*>(wb + (size_t)(n * 16 + lr) * K2 + kofs);
            acc[0][n] = __builtin_amdgcn_mfma_f32_16x16x32_bf16(a[0], bfr, acc[0][n], 0, 0, 0);
            acc[1][n] = __builtin_amdgcn_mfma_f32_16x16x32_bf16(a[1], bfr, acc[1][n], 0, 0, 0);
        }
    }

    float bv[8];
    #pragma unroll
    for (int n = 0; n < 8; ++n) bv[n] = bias[n * 16 + lr];

    #pragma unroll
    for (int m = 0; m < 2; ++m)
        #pragma unroll
        for (int j = 0; j < 4; ++j) {
            int r = row0 + m * 16 + lk * 4 + j;
            if (r < NN) {
                #pragma unroll
                for (int n = 0; n < 8; ++n)
                    out[(size_t)r * COUT + n * 16 + lr] = acc[m][n][j] + bv[n];
            }
        }
}

// ---------------- host ----------------

extern "C" void kernel_launch(void* const* d_in, const int* in_sizes, int n_in,
                              void* d_out, int out_size, void* d_ws, size_t ws_size,
                              hipStream_t stream) {
    (void)in_sizes; (void)n_in; (void)out_size;
    const float* x    = (const float*)d_in[0];
    const int*   esrc = (const int*)  d_in[1];
    const int*   edst = (const int*)  d_in[2];
    const float* wgt  = (const float*)d_in[3];
    const float* bias = (const float*)d_in[4];

    size_t ctr_ints  = 800;                              // NBIN rounded up
    size_t bin_recs  = (size_t)NBIN * CAP3;              // 1,806,336 u32
    size_t yh_elems  = (size_t)NN * CIN;                 // 12.8M ushort
    size_t need_v11 = ctr_ints * 4 + bin_recs * 4
                    + yh_elems * 2 + (size_t)K2 * COUT * 2 + 256;

    if (ws_size >= need_v11) {
        int*      wsi  = (int*)d_ws;
        int*      gctr = wsi;                            // [NBIN]
        unsigned* gbin = (unsigned*)(wsi + ctr_ints);
        ushort*   yh   = (ushort*)(gbin + bin_recs);
        ushort*   wb   = yh + yh_elems;
        float*    out  = (float*)d_out;

        k_castw<<<33, 256, 0, stream>>>(wgt, wb, gctr);  // cast + gctr zero
        k_bin  <<<NB_BIN, 256, 0, stream>>>(esrc, edst, gctr, gbin);
        k_gemm2<<<784, 256, 0, stream>>>(x, wb, bias, yh, out);
        k_p3   <<<782 * 4, 256, 0, stream>>>(gctr, gbin, yh, out);
    } else {
        int* wsi  = (int*)d_ws;
        int* cnt  = wsi;
        int* csrF = wsi + NN;
        ushort* wb = (ushort*)(wsi + NN + (size_t)NN * CAP);
        ushort* hcat = (ushort*)d_out;

        hipMemsetAsync(cnt, 0, (size_t)NN * sizeof(int), stream);
        k_fuse2<<<NB_SCAT + NB_CAST + NB_CASTW, 256, 0, stream>>>(
            x, wgt, esrc, edst, cnt, csrF, hcat, wb);
        k_aggB <<<NN / 4, 256, 0, stream>>>(cnt, csrF, hcat);
        k_gemm <<<(NN + 127) / 128, 256, 0, stream>>>(hcat, wb, bias, (float*)d_out);
    }
}

// Round 16
// 152.044 us; speedup vs baseline: 1.1394x; 1.0571x over previous
//
#include <hip/hip_runtime.h>

#define NN   100000
#define NE   1600000
#define CIN  128
#define K2   256
#define COUT 128

typedef __attribute__((ext_vector_type(8))) short bf16x8;
typedef __attribute__((ext_vector_type(4))) float f32x4;

__device__ __forceinline__ ushort f2bf(float f) {
    union { float f; unsigned u; } v; v.f = f;
    unsigned r = (v.u + 0x7FFFu + ((v.u >> 16) & 1u)) >> 16;
    return (ushort)r;
}
__device__ __forceinline__ float bflo(unsigned p) {
    union { unsigned u; float f; } v; v.u = p << 16; return v.f;
}
__device__ __forceinline__ float bfhi(unsigned p) {
    union { unsigned u; float f; } v; v.u = p & 0xFFFF0000u; return v.f;
}

// ================== V12: agg-first + single GEMM, atomic-free bins ==================
// hcat (= d_out, bf16): row r = [agg(128) | x(128)], 512 B/row
// rec = src (bits 0..16) | (dst & 127) << 17 ; bin f = dst>>7

#define NBIN     784
#define CAP3     2304
#define LCAP     8
#define NB_BIN   512
#define E_BIN    3125
#define SRCMASK  0x1FFFF
#define SCAP     1024
#define NB_CASTX 12500

// ---- W->bf16 (32 blocks) + gctr zero (1 block) + x->bf16 into hcat (12500 blocks) ----
__global__ __launch_bounds__(256) void k_castw(const float* __restrict__ w,
                                               const float* __restrict__ x,
                                               ushort* __restrict__ wb,
                                               int* __restrict__ gctr,
                                               ushort* hcat) {
    int b = blockIdx.x, t = threadIdx.x;
    if (b < 32) {
        int i = b * 256 + t;
        float4 v = *reinterpret_cast<const float4*>(w + (size_t)i * 4);
        ushort4 r; r.x = f2bf(v.x); r.y = f2bf(v.y); r.z = f2bf(v.z); r.w = f2bf(v.w);
        *reinterpret_cast<ushort4*>(wb + (size_t)i * 4) = r;
    } else if (b == 32) {
        for (int i = t; i < NBIN + 16; i += 256) gctr[i] = 0;
    } else {
        int i = (b - 33) * 256 + t;               // [0, 3.2M)
        int node = i >> 5, c4 = (i & 31) * 4;
        float4 v = *reinterpret_cast<const float4*>(x + (size_t)node * CIN + c4);
        ushort4 r; r.x = f2bf(v.x); r.y = f2bf(v.y); r.z = f2bf(v.z); r.w = f2bf(v.w);
        *reinterpret_cast<ushort4*>(hcat + ((size_t)node << 8) + CIN + c4) = r;
    }
}

// ---- single-level binning: edges -> 782 fine bins, LDS staged (r11-validated) ----
__global__ __launch_bounds__(256) void k_bin(const int* __restrict__ esrc,
                                             const int* __restrict__ edst,
                                             int* __restrict__ gctr,
                                             unsigned* __restrict__ gbin) {
    __shared__ unsigned lbuf[NBIN * LCAP];    // 25 KB
    __shared__ int      lcnt[NBIN];
    __shared__ int      lbase[NBIN];
    int b = blockIdx.x, t = threadIdx.x;
    for (int i = t; i < NBIN; i += 256) lcnt[i] = 0;
    __syncthreads();

    int base = b * E_BIN;
    for (int e = t; e < E_BIN; e += 256) {
        int d = edst[base + e], s = esrc[base + e];
        int f = d >> 7;
        unsigned rec = (unsigned)s | ((unsigned)(d & 127) << 17);
        int p = atomicAdd(&lcnt[f], 1);
        if (p < LCAP) lbuf[(f << 3) + p] = rec;
        else {
            int gp = atomicAdd(&gctr[f], 1);
            if (gp < CAP3) gbin[(size_t)f * CAP3 + gp] = rec;
        }
    }
    __syncthreads();

    for (int f = t; f < NBIN; f += 256) {
        int n = lcnt[f]; if (n > LCAP) n = LCAP;
        lcnt[f] = n;
        lbase[f] = (n > 0) ? atomicAdd(&gctr[f], n) : 0;
    }
    __syncthreads();

    for (int s = t; s < NBIN * LCAP; s += 256) {
        int f = s >> 3, k = s & 7;
        if (k < lcnt[f]) {
            int g0 = lbase[f] + k;
            if (g0 < CAP3) gbin[(size_t)f * CAP3 + g0] = lbuf[s];
        }
    }
}

// ---- p3: quarter-bin blocks, 2-pass sort, gather x-half -> write agg-half (bf16) ----
__global__ __launch_bounds__(256) void k_p3(const int* __restrict__ gctr,
                                            const unsigned* __restrict__ gbin,
                                            ushort* hcat) {
    __shared__ int ssrc[SCAP];                // 4 KB
    __shared__ int hcnt[32];
    __shared__ int hbase[32];
    __shared__ int hcur[32];
    int f   = blockIdx.x >> 2;                // bin
    int sub = blockIdx.x & 3;                 // node quarter
    int t = threadIdx.x;
    int wid = t >> 6, lane = t & 63;

    if (t < 32) hcnt[t] = 0;
    __syncthreads();

    int m = gctr[f]; if (m > CAP3) m = CAP3;
    const unsigned* recs = gbin + (size_t)f * CAP3;

    // A: histogram my quarter's nodes (read 1)
    for (int i = t; i < m; i += 256) {
        unsigned r = recs[i];
        int node = (r >> 17) & 127;
        if ((node >> 5) == sub) atomicAdd(&hcnt[node & 31], 1);
    }
    __syncthreads();

    // B: exclusive prefix over 32 counters (wave 0)
    if (t < 32) {
        int v = hcnt[t];
        int s = v;
        #pragma unroll
        for (int d = 1; d < 32; d <<= 1) {
            int u = __shfl_up(s, d);
            if (lane >= d) s += u;
        }
        hbase[t] = s - v;
        hcur[t]  = s - v;
    }
    __syncthreads();

    // C: scatter srcs into per-node contiguous lists (read 2, L2-hot)
    for (int i = t; i < m; i += 256) {
        unsigned r = recs[i];
        int node = (r >> 17) & 127;
        if ((node >> 5) == sub) {
            int p = atomicAdd(&hcur[node & 31], 1);
            if (p < SCAP) ssrc[p] = (int)(r & SRCMASK);
        }
    }
    __syncthreads();

    // D: 8 nodes per wave; wave halves process 2 edges at once (r11-validated)
    int node0 = (f << 7) + (sub << 5);
    int half = lane >> 5;
    int chof = (lane & 31) * 4;               // 4 channels per lane
    for (int i = wid * 8; i < wid * 8 + 8; ++i) {
        int n = node0 + i;
        if (n >= NN) break;
        int d0 = hbase[i], dg = hcnt[i];
        float a0 = 0.f, a1 = 0.f, a2 = 0.f, a3 = 0.f;
        for (int e = 0; e < dg; e += 8) {
            #pragma unroll
            for (int q = 0; q < 4; ++q) {
                int idx = e + q * 2 + half;
                uint2 v = make_uint2(0u, 0u);
                if (idx < dg) {
                    int s = ssrc[d0 + idx];
                    v = *reinterpret_cast<const uint2*>(hcat + ((size_t)s << 8) + CIN + chof);
                }
                a0 += bflo(v.x); a1 += bfhi(v.x);
                a2 += bflo(v.y); a3 += bfhi(v.y);
            }
        }
        a0 += __shfl(a0, lane ^ 32);
        a1 += __shfl(a1, lane ^ 32);
        a2 += __shfl(a2, lane ^ 32);
        a3 += __shfl(a3, lane ^ 32);
        float inv = (dg > 0) ? 1.0f / (float)dg : 0.0f;
        if (lane < 32) {
            ushort4 r4;
            r4.x = f2bf(a0 * inv); r4.y = f2bf(a1 * inv);
            r4.z = f2bf(a2 * inv); r4.w = f2bf(a3 * inv);
            *reinterpret_cast<ushort4*>(hcat + ((size_t)n << 8) + chof) = r4;
        }
    }
}

// ---- final GEMM: out = hcat @ W^T + bias (r5-validated, in-place on d_out) ----
__global__ __launch_bounds__(256) void k_gemm(const ushort* hcat,
                                              const ushort* __restrict__ wb,
                                              const float* __restrict__ bias,
                                              float* out) {
    int t = threadIdx.x;
    int wid = t >> 6, lane = t & 63;
    int lr = lane & 15, lk = lane >> 4;
    int row0 = blockIdx.x * 128 + wid * 32;

    f32x4 acc[2][8];
    #pragma unroll
    for (int m = 0; m < 2; ++m)
        #pragma unroll
        for (int n = 0; n < 8; ++n) acc[m][n] = (f32x4)0.f;

    #pragma unroll
    for (int kb = 0; kb < 8; ++kb) {
        int kofs = kb * 32 + lk * 8;
        bf16x8 a[2];
        #pragma unroll
        for (int m = 0; m < 2; ++m) {
            int r = row0 + m * 16 + lr; if (r >= NN) r = NN - 1;
            a[m] = *reinterpret_cast<const bf16x8*>(hcat + ((size_t)r << 8) + kofs);
        }
        #pragma unroll
        for (int n = 0; n < 8; ++n) {
            bf16x8 bfr = *reinterpret_cast<const bf16x8*>(wb + (size_t)(n * 16 + lr) * K2 + kofs);
            acc[0][n] = __builtin_amdgcn_mfma_f32_16x16x32_bf16(a[0], bfr, acc[0][n], 0, 0, 0);
            acc[1][n] = __builtin_amdgcn_mfma_f32_16x16x32_bf16(a[1], bfr, acc[1][n], 0, 0, 0);
        }
    }

    float bv[8];
    #pragma unroll
    for (int n = 0; n < 8; ++n) bv[n] = bias[n * 16 + lr];

    #pragma unroll
    for (int m = 0; m < 2; ++m)
        #pragma unroll
        for (int j = 0; j < 4; ++j) {
            int r = row0 + m * 16 + lk * 4 + j;
            if (r < NN) {
                #pragma unroll
                for (int n = 0; n < 8; ++n)
                    out[(size_t)r * COUT + n * 16 + lr] = acc[m][n][j] + bv[n];
            }
        }
}

// ======================= V2 fallback (round-5, validated) =======================

#define NXCD  8
#define PART  ((NN + NXCD - 1) / NXCD)
#define NB_SCAT  2048
#define NB_CAST  12500
#define NB_CASTW 32
#define CAP  64

__global__ __launch_bounds__(256) void k_fuse2(const float* __restrict__ x,
                                               const float* __restrict__ w,
                                               const int* __restrict__ src,
                                               const int* __restrict__ dst,
                                               int* __restrict__ cnt,
                                               int* __restrict__ csrF,
                                               ushort* hcat,
                                               ushort* __restrict__ wb) {
    int b = blockIdx.x, t = threadIdx.x;
    if (b < NB_SCAT) {
        int part = b & (NXCD - 1);
        int slot = b >> 3;
        int lo = part * PART;
        int hi = lo + PART; if (hi > NN) hi = NN;
        const int NCH = NE / 4;
        for (int c = slot * 256 + t; c < NCH; c += 256 * 256) {
            int4 d = *reinterpret_cast<const int4*>(dst + (size_t)c * 4);
            int4 s = *reinterpret_cast<const int4*>(src + (size_t)c * 4);
            if (d.x >= lo && d.x < hi) { int p = atomicAdd(&cnt[d.x], 1); csrF[(d.x << 6) + p] = s.x; }
            if (d.y >= lo && d.y < hi) { int p = atomicAdd(&cnt[d.y], 1); csrF[(d.y << 6) + p] = s.y; }
            if (d.z >= lo && d.z < hi) { int p = atomicAdd(&cnt[d.z], 1); csrF[(d.z << 6) + p] = s.z; }
            if (d.w >= lo && d.w < hi) { int p = atomicAdd(&cnt[d.w], 1); csrF[(d.w << 6) + p] = s.w; }
        }
    } else if (b < NB_SCAT + NB_CAST) {
        int i = (b - NB_SCAT) * 256 + t;
        int node = i >> 5, c4 = (i & 31) * 4;
        float4 v = *reinterpret_cast<const float4*>(x + (size_t)node * CIN + c4);
        ushort4 r; r.x = f2bf(v.x); r.y = f2bf(v.y); r.z = f2bf(v.z); r.w = f2bf(v.w);
        *reinterpret_cast<ushort4*>(hcat + (size_t)node * K2 + CIN + c4) = r;
    } else {
        int i = (b - NB_SCAT - NB_CAST) * 256 + t;
        float4 v = *reinterpret_cast<const float4*>(w + (size_t)i * 4);
        ushort4 r; r.x = f2bf(v.x); r.y = f2bf(v.y); r.z = f2bf(v.z); r.w = f2bf(v.w);
        *reinterpret_cast<ushort4*>(wb + (size_t)i * 4) = r;
    }
}

__global__ __launch_bounds__(256) void k_aggB(const int* __restrict__ cnt,
                                              const int* __restrict__ csrF,
                                              ushort* hcat) {
    int gw   = (blockIdx.x * 256 + threadIdx.x) >> 6;
    int lane = threadIdx.x & 63;
    if (gw >= NN) return;
    int gws = __builtin_amdgcn_readfirstlane(gw);
    int deg = cnt[gws];
    const int4* b4 = reinterpret_cast<const int4*>(csrF + ((size_t)gws << 6));
    int boff = CIN + lane * 2;
    float ax = 0.f, ay = 0.f;
    for (int e = 0; e < deg; e += 8) {
        int4 c0 = b4[(e >> 2)];
        int4 c1 = b4[(e >> 2) + 1];
        int ss[8] = {c0.x, c0.y, c0.z, c0.w, c1.x, c1.y, c1.z, c1.w};
        #pragma unroll
        for (int k = 0; k < 8; ++k) {
            bool ok = (e + k) < deg;
            int s = ok ? ss[k] : 0;
            unsigned v = *reinterpret_cast<const unsigned*>(hcat + ((size_t)s << 8) + boff);
            float mq = ok ? 1.f : 0.f;
            ax += mq * bflo(v); ay += mq * bfhi(v);
        }
    }
    float inv = (deg > 0) ? 1.0f / (float)deg : 0.0f;
    unsigned packed = (unsigned)f2bf(ax * inv) | ((unsigned)f2bf(ay * inv) << 16);
    *reinterpret_cast<unsigned*>(hcat + ((size_t)gw << 8) + lane * 2) = packed;
}

// ---------------- host ----------------

extern "C" void kernel_launch(void* const* d_in, const int* in_sizes, int n_in,
                              void* d_out, int out_size, void* d_ws, size_t ws_size,
                              hipStream_t stream) {
    (void)in_sizes; (void)n_in; (void)out_size;
    const float* x    = (const float*)d_in[0];
    const int*   esrc = (const int*)  d_in[1];
    const int*   edst = (const int*)  d_in[2];
    const float* wgt  = (const float*)d_in[3];
    const float* bias = (const float*)d_in[4];

    size_t ctr_ints  = 800;                              // NBIN rounded up
    size_t bin_recs  = (size_t)NBIN * CAP3;              // 1,806,336 u32
    size_t need_v12 = ctr_ints * 4 + bin_recs * 4 + (size_t)K2 * COUT * 2 + 256;

    ushort* hcat = (ushort*)d_out;        // rows: [agg bf16(128) | x bf16(128)]

    if (ws_size >= need_v12) {
        int*      wsi  = (int*)d_ws;
        int*      gctr = wsi;                            // [NBIN]
        unsigned* gbin = (unsigned*)(wsi + ctr_ints);
        ushort*   wb   = (ushort*)(gbin + bin_recs);
        float*    out  = (float*)d_out;

        k_castw<<<33 + NB_CASTX, 256, 0, stream>>>(wgt, x, wb, gctr, hcat);
        k_bin  <<<NB_BIN, 256, 0, stream>>>(esrc, edst, gctr, gbin);
        k_p3   <<<782 * 4, 256, 0, stream>>>(gctr, gbin, hcat);
        k_gemm <<<(NN + 127) / 128, 256, 0, stream>>>(hcat, wb, bias, out);
    } else {
        int* wsi  = (int*)d_ws;
        int* cnt  = wsi;
        int* csrF = wsi + NN;
        ushort* wb = (ushort*)(wsi + NN + (size_t)NN * CAP);

        hipMemsetAsync(cnt, 0, (size_t)NN * sizeof(int), stream);
        k_fuse2<<<NB_SCAT + NB_CAST + NB_CASTW, 256, 0, stream>>>(
            x, wgt, esrc, edst, cnt, csrF, hcat, wb);
        k_aggB <<<NN / 4, 256, 0, stream>>>(cnt, csrF, hcat);
        k_gemm <<<(NN + 127) / 128, 256, 0, stream>>>(hcat, wb, bias, (float*)d_out);
    }
}

// Round 17
// 126.522 us; speedup vs baseline: 1.3693x; 1.2017x over previous
//
#include <hip/hip_runtime.h>

#define NN   100000
#define NE   1600000
#define CIN  128
#define K2   256
#define COUT 128

typedef __attribute__((ext_vector_type(8))) short bf16x8;
typedef __attribute__((ext_vector_type(4))) float f32x4;

__device__ __forceinline__ ushort f2bf(float f) {
    union { float f; unsigned u; } v; v.f = f;
    unsigned r = (v.u + 0x7FFFu + ((v.u >> 16) & 1u)) >> 16;
    return (ushort)r;
}
__device__ __forceinline__ float bflo(unsigned p) {
    union { unsigned u; float f; } v; v.u = p << 16; return v.f;
}
__device__ __forceinline__ float bfhi(unsigned p) {
    union { unsigned u; float f; } v; v.u = p & 0xFFFF0000u; return v.f;
}

// ============ V13: epilogue-fused p3 (agg->LDS->MFMA->out), castx||bin ============
// xp (ws, bf16): x rows, 256 B each — gather pool, never overwritten.
// rec = src (bits 0..16) | (dst & 127) << 17 ; bin f = dst>>7

#define NBIN     784
#define CAP3     2304
#define LCAP     8
#define NB_BIN   512
#define E_BIN    3125
#define SRCMASK  0x1FFFF
#define SCAP     1024
#define NB_CASTX 12500
#define KSTR     264       // kS row stride (256 + 8 pad), elems

// ---- k_pre: W->bf16 (blocks 0-31) + gctr zero (block 32) ----
__global__ __launch_bounds__(256) void k_pre(const float* __restrict__ w,
                                             ushort* __restrict__ wb,
                                             int* __restrict__ gctr) {
    int t = threadIdx.x;
    if (blockIdx.x < 32) {
        int i = blockIdx.x * 256 + t;
        float4 v = *reinterpret_cast<const float4*>(w + (size_t)i * 4);
        ushort4 r; r.x = f2bf(v.x); r.y = f2bf(v.y); r.z = f2bf(v.z); r.w = f2bf(v.w);
        *reinterpret_cast<ushort4*>(wb + (size_t)i * 4) = r;
    } else {
        for (int i = t; i < NBIN + 16; i += 256) gctr[i] = 0;
    }
}

// ---- k_cb: edge binning (blocks 0-511) || x->bf16 cast into xp (rest) ----
__global__ __launch_bounds__(256) void k_cb(const float* __restrict__ x,
                                            const int* __restrict__ esrc,
                                            const int* __restrict__ edst,
                                            int* __restrict__ gctr,
                                            unsigned* __restrict__ gbin,
                                            ushort* __restrict__ xp) {
    __shared__ unsigned lbuf[NBIN * LCAP];    // 25 KB (bin role only)
    __shared__ int      lcnt[NBIN];
    __shared__ int      lbase[NBIN];
    int b = blockIdx.x, t = threadIdx.x;

    if (b < NB_BIN) {
        for (int i = t; i < NBIN; i += 256) lcnt[i] = 0;
        __syncthreads();

        int base = b * E_BIN;
        for (int e = t; e < E_BIN; e += 256) {
            int d = edst[base + e], s = esrc[base + e];
            int f = d >> 7;
            unsigned rec = (unsigned)s | ((unsigned)(d & 127) << 17);
            int p = atomicAdd(&lcnt[f], 1);
            if (p < LCAP) lbuf[(f << 3) + p] = rec;
            else {
                int gp = atomicAdd(&gctr[f], 1);
                if (gp < CAP3) gbin[(size_t)f * CAP3 + gp] = rec;
            }
        }
        __syncthreads();

        for (int f = t; f < NBIN; f += 256) {
            int n = lcnt[f]; if (n > LCAP) n = LCAP;
            lcnt[f] = n;
            lbase[f] = (n > 0) ? atomicAdd(&gctr[f], n) : 0;
        }
        __syncthreads();

        for (int s = t; s < NBIN * LCAP; s += 256) {
            int f = s >> 3, k = s & 7;
            if (k < lcnt[f]) {
                int g0 = lbase[f] + k;
                if (g0 < CAP3) gbin[(size_t)f * CAP3 + g0] = lbuf[s];
            }
        }
    } else {
        int i = (b - NB_BIN) * 256 + t;           // [0, 3.2M)
        int node = i >> 5, c4 = (i & 31) * 4;
        float4 v = *reinterpret_cast<const float4*>(x + (size_t)node * CIN + c4);
        ushort4 r; r.x = f2bf(v.x); r.y = f2bf(v.y); r.z = f2bf(v.z); r.w = f2bf(v.w);
        *reinterpret_cast<ushort4*>(xp + ((size_t)node << 7) + c4) = r;
    }
}

// ---- p3: quarter-bin blocks; sort -> gather -> agg in LDS -> fused 32-row GEMM ----
__global__ __launch_bounds__(256) void k_p3(const int* __restrict__ gctr,
                                            const unsigned* __restrict__ gbin,
                                            const ushort* __restrict__ xp,
                                            const ushort* __restrict__ wb,
                                            const float* __restrict__ bias,
                                            float* __restrict__ out) {
    __shared__ int    ssrc[SCAP];             // 4 KB
    __shared__ int    hcnt[32];
    __shared__ int    hbase[32];
    __shared__ int    hcur[32];
    __shared__ ushort kS[32 * KSTR];          // 16.5 KB: [agg(128) | x(128) | pad]
    int f   = blockIdx.x >> 2;                // bin
    int sub = blockIdx.x & 3;                 // node quarter
    int node0 = (f << 7) + (sub << 5);
    if (node0 >= NN) return;                  // empty tail quarters
    int t = threadIdx.x;
    int wid = t >> 6, lane = t & 63;

    if (t < 32) hcnt[t] = 0;
    __syncthreads();

    int m = gctr[f]; if (m > CAP3) m = CAP3;
    const unsigned* recs = gbin + (size_t)f * CAP3;

    // A: histogram my quarter's nodes (read 1)
    for (int i = t; i < m; i += 256) {
        unsigned r = recs[i];
        int node = (r >> 17) & 127;
        if ((node >> 5) == sub) atomicAdd(&hcnt[node & 31], 1);
    }
    __syncthreads();

    // B: exclusive prefix over 32 counters (wave 0)
    if (t < 32) {
        int v = hcnt[t];
        int s = v;
        #pragma unroll
        for (int d = 1; d < 32; d <<= 1) {
            int u = __shfl_up(s, d);
            if (lane >= d) s += u;
        }
        hbase[t] = s - v;
        hcur[t]  = s - v;
    }
    __syncthreads();

    // C: scatter srcs into per-node contiguous lists (read 2, L2-hot)
    for (int i = t; i < m; i += 256) {
        unsigned r = recs[i];
        int node = (r >> 17) & 127;
        if ((node >> 5) == sub) {
            int p = atomicAdd(&hcur[node & 31], 1);
            if (p < SCAP) ssrc[p] = (int)(r & SRCMASK);
        }
    }
    __syncthreads();

    // D: gather+reduce 8 nodes per wave; write agg (bf16) into kS cols [0,128)
    int half = lane >> 5;
    int chof = (lane & 31) * 4;               // 4 channels per lane
    for (int i = wid * 8; i < wid * 8 + 8; ++i) {
        int d0 = hbase[i], dg = hcnt[i];
        float a0 = 0.f, a1 = 0.f, a2 = 0.f, a3 = 0.f;
        for (int e = 0; e < dg; e += 8) {
            #pragma unroll
            for (int q = 0; q < 4; ++q) {
                int idx = e + q * 2 + half;
                uint2 v = make_uint2(0u, 0u);
                if (idx < dg) {
                    int s = ssrc[d0 + idx];
                    v = *reinterpret_cast<const uint2*>(xp + ((size_t)s << 7) + chof);
                }
                a0 += bflo(v.x); a1 += bfhi(v.x);
                a2 += bflo(v.y); a3 += bfhi(v.y);
            }
        }
        a0 += __shfl(a0, lane ^ 32);
        a1 += __shfl(a1, lane ^ 32);
        a2 += __shfl(a2, lane ^ 32);
        a3 += __shfl(a3, lane ^ 32);
        float inv = (dg > 0) ? 1.0f / (float)dg : 0.0f;
        if (lane < 32) {
            ushort4 r4;
            r4.x = f2bf(a0 * inv); r4.y = f2bf(a1 * inv);
            r4.z = f2bf(a2 * inv); r4.w = f2bf(a3 * inv);
            *reinterpret_cast<ushort4*>(&kS[i * KSTR + chof]) = r4;
        }
    }

    // E0: stage this block's 32 x-rows into kS cols [128,256)  (disjoint from D's cols)
    for (int g = t; g < 32 * 16; g += 256) {
        int row = g >> 4, col8 = (g & 15) * 8;
        bf16x8 v = *reinterpret_cast<const bf16x8*>(xp + ((size_t)(node0 + row) << 7) + col8);
        *reinterpret_cast<bf16x8*>(&kS[row * KSTR + CIN + col8]) = v;
    }
    __syncthreads();

    // E1: 32-row GEMM: out[node0..+32] = kS(32x256) @ W^T + bias
    int lr = lane & 15, lk = lane >> 4;
    f32x4 acc[2][2];
    #pragma unroll
    for (int mm = 0; mm < 2; ++mm)
        #pragma unroll
        for (int ni = 0; ni < 2; ++ni) acc[mm][ni] = (f32x4)0.f;

    #pragma unroll
    for (int kb = 0; kb < 8; ++kb) {
        int kofs = kb * 32 + lk * 8;
        bf16x8 a0 = *reinterpret_cast<const bf16x8*>(&kS[lr * KSTR + kofs]);
        bf16x8 a1 = *reinterpret_cast<const bf16x8*>(&kS[(16 + lr) * KSTR + kofs]);
        #pragma unroll
        for (int ni = 0; ni < 2; ++ni) {
            int nt = wid * 2 + ni;
            bf16x8 bfr = *reinterpret_cast<const bf16x8*>(wb + (size_t)(nt * 16 + lr) * K2 + kofs);
            acc[0][ni] = __builtin_amdgcn_mfma_f32_16x16x32_bf16(a0, bfr, acc[0][ni], 0, 0, 0);
            acc[1][ni] = __builtin_amdgcn_mfma_f32_16x16x32_bf16(a1, bfr, acc[1][ni], 0, 0, 0);
        }
    }

    float bv[2];
    #pragma unroll
    for (int ni = 0; ni < 2; ++ni) bv[ni] = bias[(wid * 2 + ni) * 16 + lr];

    // C/D layout: col = lane&15, row = (lane>>4)*4 + j   [m89/m91 verified]
    #pragma unroll
    for (int mm = 0; mm < 2; ++mm)
        #pragma unroll
        for (int j = 0; j < 4; ++j) {
            int r = node0 + mm * 16 + lk * 4 + j;
            #pragma unroll
            for (int ni = 0; ni < 2; ++ni)
                out[(size_t)r * COUT + (wid * 2 + ni) * 16 + lr] = acc[mm][ni][j] + bv[ni];
        }
}

// ======================= V2 fallback (round-5, validated) =======================

#define NXCD  8
#define PART  ((NN + NXCD - 1) / NXCD)
#define NB_SCAT  2048
#define NB_CAST  12500
#define NB_CASTW 32
#define CAP  64

__global__ __launch_bounds__(256) void k_fuse2(const float* __restrict__ x,
                                               const float* __restrict__ w,
                                               const int* __restrict__ src,
                                               const int* __restrict__ dst,
                                               int* __restrict__ cnt,
                                               int* __restrict__ csrF,
                                               ushort* hcat,
                                               ushort* __restrict__ wb) {
    int b = blockIdx.x, t = threadIdx.x;
    if (b < NB_SCAT) {
        int part = b & (NXCD - 1);
        int slot = b >> 3;
        int lo = part * PART;
        int hi = lo + PART; if (hi > NN) hi = NN;
        const int NCH = NE / 4;
        for (int c = slot * 256 + t; c < NCH; c += 256 * 256) {
            int4 d = *reinterpret_cast<const int4*>(dst + (size_t)c * 4);
            int4 s = *reinterpret_cast<const int4*>(src + (size_t)c * 4);
            if (d.x >= lo && d.x < hi) { int p = atomicAdd(&cnt[d.x], 1); csrF[(d.x << 6) + p] = s.x; }
            if (d.y >= lo && d.y < hi) { int p = atomicAdd(&cnt[d.y], 1); csrF[(d.y << 6) + p] = s.y; }
            if (d.z >= lo && d.z < hi) { int p = atomicAdd(&cnt[d.z], 1); csrF[(d.z << 6) + p] = s.z; }
            if (d.w >= lo && d.w < hi) { int p = atomicAdd(&cnt[d.w], 1); csrF[(d.w << 6) + p] = s.w; }
        }
    } else if (b < NB_SCAT + NB_CAST) {
        int i = (b - NB_SCAT) * 256 + t;
        int node = i >> 5, c4 = (i & 31) * 4;
        float4 v = *reinterpret_cast<const float4*>(x + (size_t)node * CIN + c4);
        ushort4 r; r.x = f2bf(v.x); r.y = f2bf(v.y); r.z = f2bf(v.z); r.w = f2bf(v.w);
        *reinterpret_cast<ushort4*>(hcat + (size_t)node * K2 + CIN + c4) = r;
    } else {
        int i = (b - NB_SCAT - NB_CAST) * 256 + t;
        float4 v = *reinterpret_cast<const float4*>(w + (size_t)i * 4);
        ushort4 r; r.x = f2bf(v.x); r.y = f2bf(v.y); r.z = f2bf(v.z); r.w = f2bf(v.w);
        *reinterpret_cast<ushort4*>(wb + (size_t)i * 4) = r;
    }
}

__global__ __launch_bounds__(256) void k_aggB(const int* __restrict__ cnt,
                                              const int* __restrict__ csrF,
                                              ushort* hcat) {
    int gw   = (blockIdx.x * 256 + threadIdx.x) >> 6;
    int lane = threadIdx.x & 63;
    if (gw >= NN) return;
    int gws = __builtin_amdgcn_readfirstlane(gw);
    int deg = cnt[gws];
    const int4* b4 = reinterpret_cast<const int4*>(csrF + ((size_t)gws << 6));
    int boff = CIN + lane * 2;
    float ax = 0.f, ay = 0.f;
    for (int e = 0; e < deg; e += 8) {
        int4 c0 = b4[(e >> 2)];
        int4 c1 = b4[(e >> 2) + 1];
        int ss[8] = {c0.x, c0.y, c0.z, c0.w, c1.x, c1.y, c1.z, c1.w};
        #pragma unroll
        for (int k = 0; k < 8; ++k) {
            bool ok = (e + k) < deg;
            int s = ok ? ss[k] : 0;
            unsigned v = *reinterpret_cast<const unsigned*>(hcat + ((size_t)s << 8) + boff);
            float mq = ok ? 1.f : 0.f;
            ax += mq * bflo(v); ay += mq * bfhi(v);
        }
    }
    float inv = (deg > 0) ? 1.0f / (float)deg : 0.0f;
    unsigned packed = (unsigned)f2bf(ax * inv) | ((unsigned)f2bf(ay * inv) << 16);
    *reinterpret_cast<unsigned*>(hcat + ((size_t)gw << 8) + lane * 2) = packed;
}

__global__ __launch_bounds__(256) void k_gemm(const ushort* hcat,
                                              const ushort* __restrict__ wb,
                                              const float* __restrict__ bias,
                                              float* out) {
    int t = threadIdx.x;
    int wid = t >> 6, lane = t & 63;
    int lr = lane & 15, lk = lane >> 4;
    int row0 = blockIdx.x * 128 + wid * 32;

    f32x4 acc[2][8];
    #pragma unroll
    for (int m = 0; m < 2; ++m)
        #pragma unroll
        for (int n = 0; n < 8; ++n) acc[m][n] = (f32x4)0.f;

    #pragma unroll
    for (int kb = 0; kb < 8; ++kb) {
        int kofs = kb * 32 + lk * 8;
        bf16x8 a[2];
        #pragma unroll
        for (int m = 0; m < 2; ++m) {
            int r = row0 + m * 16 + lr; if (r >= NN) r = NN - 1;
            a[m] = *reinterpret_cast<const bf16x8*>(hcat + ((size_t)r << 8) + kofs);
        }
        #pragma unroll
        for (int n = 0; n < 8; ++n) {
            bf16x8 bfr = *reinterpret_cast<const bf16x8*>(wb + (size_t)(n * 16 + lr) * K2 + kofs);
            acc[0][n] = __builtin_amdgcn_mfma_f32_16x16x32_bf16(a[0], bfr, acc[0][n], 0, 0, 0);
            acc[1][n] = __builtin_amdgcn_mfma_f32_16x16x32_bf16(a[1], bfr, acc[1][n], 0, 0, 0);
        }
    }

    float bv[8];
    #pragma unroll
    for (int n = 0; n < 8; ++n) bv[n] = bias[n * 16 + lr];

    #pragma unroll
    for (int m = 0; m < 2; ++m)
        #pragma unroll
        for (int j = 0; j < 4; ++j) {
            int r = row0 + m * 16 + lk * 4 + j;
            if (r < NN) {
                #pragma unroll
                for (int n = 0; n < 8; ++n)
                    out[(size_t)r * COUT + n * 16 + lr] = acc[m][n][j] + bv[n];
            }
        }
}

// ---------------- host ----------------

extern "C" void kernel_launch(void* const* d_in, const int* in_sizes, int n_in,
                              void* d_out, int out_size, void* d_ws, size_t ws_size,
                              hipStream_t stream) {
    (void)in_sizes; (void)n_in; (void)out_size;
    const float* x    = (const float*)d_in[0];
    const int*   esrc = (const int*)  d_in[1];
    const int*   edst = (const int*)  d_in[2];
    const float* wgt  = (const float*)d_in[3];
    const float* bias = (const float*)d_in[4];

    size_t ctr_ints = 800;                               // NBIN rounded up
    size_t bin_recs = (size_t)NBIN * CAP3;               // 1,806,336 u32
    size_t xp_elems = (size_t)NN * CIN;                  // 12.8M ushort
    size_t need_v13 = ctr_ints * 4 + bin_recs * 4 + xp_elems * 2
                    + (size_t)K2 * COUT * 2 + 256;       // ~33 MB

    if (ws_size >= need_v13) {
        int*      wsi  = (int*)d_ws;
        int*      gctr = wsi;                            // [NBIN]
        unsigned* gbin = (unsigned*)(wsi + ctr_ints);
        ushort*   xp   = (ushort*)(gbin + bin_recs);     // x pool (never overwritten)
        ushort*   wb   = xp + xp_elems;
        float*    out  = (float*)d_out;

        k_pre<<<33, 256, 0, stream>>>(wgt, wb, gctr);
        k_cb <<<NB_BIN + NB_CASTX, 256, 0, stream>>>(x, esrc, edst, gctr, gbin, xp);
        k_p3 <<<782 * 4, 256, 0, stream>>>(gctr, gbin, xp, wb, bias, out);
    } else {
        int* wsi  = (int*)d_ws;
        int* cnt  = wsi;
        int* csrF = wsi + NN;
        ushort* wb = (ushort*)(wsi + NN + (size_t)NN * CAP);
        ushort* hcat = (ushort*)d_out;

        hipMemsetAsync(cnt, 0, (size_t)NN * sizeof(int), stream);
        k_fuse2<<<NB_SCAT + NB_CAST + NB_CASTW, 256, 0, stream>>>(
            x, wgt, esrc, edst, cnt, csrF, hcat, wb);
        k_aggB <<<NN / 4, 256, 0, stream>>>(cnt, csrF, hcat);
        k_gemm <<<(NN + 127) / 128, 256, 0, stream>>>(hcat, wb, bias, (float*)d_out);
    }
}